// Round 11
// baseline (435.993 us; speedup 1.0000x reference)
//
#include <hip/hip_runtime.h>
#include <hip/hip_bf16.h>

typedef __bf16 bf16;
typedef __bf16 bf16x4v __attribute__((ext_vector_type(4)));
typedef __bf16 bf16x8v __attribute__((ext_vector_type(8)));
typedef float f32x4 __attribute__((ext_vector_type(4)));
typedef short s16x4 __attribute__((ext_vector_type(4)));

#define DEVINL static __device__ __forceinline__
#define AS1 __attribute__((address_space(1)))
#define AS3 __attribute__((address_space(3)))

DEVINL f32x4 mfma16(bf16x8v a, bf16x8v b, f32x4 c) {
  return __builtin_amdgcn_mfma_f32_16x16x32_bf16(a, b, c, 0, 0, 0);
}

// 16x16x16 bf16 MFMA: A/B frag = 4 bf16 (k = (l>>4)*4+u), C/D standard.
DEVINL f32x4 mfma16x16(bf16x4v a, bf16x4v b, f32x4 c) {
#if __has_builtin(__builtin_amdgcn_mfma_f32_16x16x16bf16_1k)
  return __builtin_amdgcn_mfma_f32_16x16x16bf16_1k(
      __builtin_bit_cast(s16x4, a), __builtin_bit_cast(s16x4, b), c, 0, 0, 0);
#else
  f32x4 d;
  asm("v_mfma_f32_16x16x16_bf16 %0, %1, %2, %3"
      : "=v"(d) : "v"(a), "v"(b), "v"(c));
  return d;
#endif
}

// ---------------- style projections: s = style @ w_ada + b_ada (f32) --------
__global__ __launch_bounds__(256) void k_style(
    const float* __restrict__ style,
    const float* __restrict__ wa1, const float* __restrict__ ba1,
    const float* __restrict__ wa2, const float* __restrict__ ba2,
    float* __restrict__ s1, float* __restrict__ s2) {
  int bid = blockIdx.x;
  int ng = bid & 31, b = (bid >> 5) & 15, which = bid >> 9;
  int tid = threadIdx.x;
  int nl = tid & 15, kg = tid >> 4;
  int n = ng * 16 + nl;
  const float* wa = which ? wa2 : wa1;
  const float* ba = which ? ba2 : ba1;
  const float* srow = style + b * 512;
  float acc = 0.f;
  #pragma unroll 8
  for (int kk = 0; kk < 32; ++kk) {
    int k = kg + kk * 16;
    acc += srow[k] * wa[k * 512 + n];
  }
  acc += __shfl_xor(acc, 16);
  acc += __shfl_xor(acc, 32);
  __shared__ float red[4][16];
  int l = tid & 63, w = tid >> 6;
  if (l < 16) red[w][nl] = acc;
  __syncthreads();
  if (tid < 16) {
    float S = red[0][tid] + red[1][tid] + red[2][tid] + red[3][tid]
            + ba[ng * 16 + tid];
    (which ? s2 : s1)[b * 512 + ng * 16 + tid] = S;
  }
}

// ---------------- stats pass 1: per (b, row-chunk) partial sum/sumsq --------
template<int F32>
__global__ __launch_bounds__(256) void k_stats_part(
    const void* __restrict__ xv, float* __restrict__ psum,
    float* __restrict__ psq) {
  int rc = blockIdx.x, b = blockIdx.y;
  int c = threadIdx.x;
  size_t base = (size_t)b * 4096 * 256 + (size_t)rc * 256 * 256 + c;
  float sm = 0.f, q = 0.f;
  #pragma unroll 4
  for (int r = 0; r < 256; ++r) {
    float f;
    if constexpr (F32) f = ((const float*)xv)[base + (size_t)r * 256];
    else               f = (float)((const bf16*)xv)[base + (size_t)r * 256];
    sm += f; q += f * f;
  }
  int o = (b * 16 + rc) * 256 + c;
  psum[o] = sm; psq[o] = q;
}

// ---------------- stats pass 2: combine + adain scale/shift -----------------
__global__ __launch_bounds__(256) void k_stats_fin(
    const float* __restrict__ psum, const float* __restrict__ psq,
    const float* __restrict__ s,
    float* __restrict__ scale, float* __restrict__ shift) {
  int b = blockIdx.x, c = threadIdx.x;
  float S = 0.f, Q = 0.f;
  #pragma unroll
  for (int rc = 0; rc < 16; ++rc) {
    S += psum[(b * 16 + rc) * 256 + c];
    Q += psq[(b * 16 + rc) * 256 + c];
  }
  float mean = S * (1.0f/4096.0f);
  float var  = Q * (1.0f/4096.0f) - mean * mean;
  float inv  = rsqrtf(var + 1e-5f);
  float mu_s  = s[b * 512 + c];
  float std_s = s[b * 512 + 256 + c];
  float sc = std_s * inv;
  scale[b * 256 + c] = sc;
  shift[b * 256 + c] = mu_s - sc * mean;
}

// ---------------- adain apply: out_bf16 = shift + scale * in ----------------
template<int F32>
__global__ __launch_bounds__(256) void k_adain(
    const void* __restrict__ in, const float* __restrict__ scale,
    const float* __restrict__ shift, bf16* __restrict__ out) {
  int idx = blockIdx.x * 256 + threadIdx.x;
  int c8 = idx & 31, row = idx >> 5;
  int b = row >> 12, c = c8 * 8;
  const float* scp = &scale[b * 256 + c];
  const float* shp = &shift[b * 256 + c];
  f32x4 sc0 = *(const f32x4*)scp, sc1 = *(const f32x4*)(scp + 4);
  f32x4 sh0 = *(const f32x4*)shp, sh1 = *(const f32x4*)(shp + 4);
  size_t ofs = (size_t)row * 256 + c;
  float f[8];
  if constexpr (F32) {
    f32x4 v0 = *(const f32x4*)&((const float*)in)[ofs];
    f32x4 v1 = *(const f32x4*)&((const float*)in)[ofs + 4];
    f[0]=v0[0]; f[1]=v0[1]; f[2]=v0[2]; f[3]=v0[3];
    f[4]=v1[0]; f[5]=v1[1]; f[6]=v1[2]; f[7]=v1[3];
  } else {
    bf16x8v v = *(const bf16x8v*)&((const bf16*)in)[ofs];
    #pragma unroll
    for (int u = 0; u < 8; ++u) f[u] = (float)v[u];
  }
  bf16x8v o;
  o[0]=(bf16)(sh0[0]+sc0[0]*f[0]); o[1]=(bf16)(sh0[1]+sc0[1]*f[1]);
  o[2]=(bf16)(sh0[2]+sc0[2]*f[2]); o[3]=(bf16)(sh0[3]+sc0[3]*f[3]);
  o[4]=(bf16)(sh1[0]+sc1[0]*f[4]); o[5]=(bf16)(sh1[1]+sc1[1]*f[5]);
  o[6]=(bf16)(sh1[2]+sc1[2]*f[6]); o[7]=(bf16)(sh1[3]+sc1[3]*f[7]);
  *(bf16x8v*)&out[ofs] = o;
}

// ---------------- weight transpose+cvt (K x N f32) -> (N x K bf16) ----------
__global__ __launch_bounds__(256) void k_tr(
    const float* __restrict__ in, bf16* __restrict__ out, int K, int N) {
  __shared__ float t[32][33];
  int bx = blockIdx.x * 32, by = blockIdx.y * 32;
  int tx = threadIdx.x & 31, ty = threadIdx.x >> 5;
  #pragma unroll
  for (int r = 0; r < 32; r += 8)
    t[ty + r][tx] = in[(size_t)(by + ty + r) * N + bx + tx];
  __syncthreads();
  #pragma unroll
  for (int r = 0; r < 32; r += 8)
    out[(size_t)(bx + ty + r) * K + by + tx] = (bf16)t[tx][ty + r];
}

// ---------------- streaming GEMM: out = A @ Bt^T + bias (+res, gelu) --------
// BM=256 (4 waves x 64 rows) x BN=64. B slab (64 x 256K = 32 KB) resident in
// LDS, XOR-swizzled (chunk^=row&7, both-sides involution); A streamed straight
// global->registers (no LDS, no per-K-step barriers). K = multiple of 256;
// per 256-slab: 2 barriers total. This removes the vmcnt(0)-drain-per-K-step
// serialization of the classic 2-barrier structure (r10: both pipes ~21%).
// RESMODE: 0 none, 1 f32, 2 bf16. OUTF32: 1 f32 out, 0 bf16 out.
template<int RESMODE, int GELU, int OUTF32>
__global__ __launch_bounds__(256) void k_gemm_stream(
    const bf16* __restrict__ A, const bf16* __restrict__ Bt,
    const float* __restrict__ bias, const void* __restrict__ resv,
    void* __restrict__ outv, int N, int K, int gx) {
  __shared__ bf16 b_sw[64 * 256];   // 32 KB
  int tid = threadIdx.x;
  int l = tid & 63, w = tid >> 6;
  int lm = l & 15, lg = l >> 4;

  int nwg = gridDim.x;
  int lin = blockIdx.x;
  int swz = (lin & 7) * (nwg >> 3) + (lin >> 3);
  int bx = swz % gx, by = swz / gx;
  int m0 = by * 256, n0 = bx * 64;

  // per-lane A row pointers (4 row-blocks of this wave's 64 rows)
  const bf16* pA[4];
  #pragma unroll
  for (int mi = 0; mi < 4; ++mi)
    pA[mi] = A + (size_t)(m0 + w * 64 + mi * 16 + lm) * K + lg * 8;

  f32x4 acc[4][4];
  #pragma unroll
  for (int mi = 0; mi < 4; ++mi)
    #pragma unroll
    for (int ni = 0; ni < 4; ++ni)
      acc[mi][ni] = (f32x4){0.f, 0.f, 0.f, 0.f};

  for (int ks = 0; ks < K; ks += 256) {
    if (ks) __syncthreads();             // all waves done with previous slab
    // stage B slab: 64 rows x 256 K = 2048 16B chunks, 8 per thread.
    // linear LDS dest + inverse-swizzled global source (chunk ^= row&7).
    #pragma unroll
    for (int i = 0; i < 8; ++i) {
      int slot = i * 256 + tid;
      int r = slot >> 5, c = slot & 31;
      int cs = c ^ (r & 7);
      const bf16* g = Bt + (size_t)(n0 + r) * K + ks + cs * 8;
      __builtin_amdgcn_global_load_lds(
          (const AS1 void*)g,
          (AS3 void*)(b_sw + (size_t)(i * 256 + w * 64) * 8), 16, 0, 0);
    }
    __syncthreads();                     // slab ready (vmcnt drained)

    // barrier-free K-inner loop: 8 x {4 A-loads, 4 ds_reads, 16 MFMA}
    #pragma unroll
    for (int kk = 0; kk < 8; ++kk) {
      bf16x8v af[4], bv[4];
      #pragma unroll
      for (int mi = 0; mi < 4; ++mi)
        af[mi] = *(const bf16x8v*)(pA[mi] + ks + kk * 32);
      #pragma unroll
      for (int ni = 0; ni < 4; ++ni) {
        int row = ni * 16 + lm;
        bv[ni] = *(const bf16x8v*)&b_sw[row * 256 + (((kk * 4 + lg) ^ (row & 7)) * 8)];
      }
      #pragma unroll
      for (int mi = 0; mi < 4; ++mi)
        #pragma unroll
        for (int ni = 0; ni < 4; ++ni)
          acc[mi][ni] = mfma16(af[mi], bv[ni], acc[mi][ni]);
    }
  }

  #pragma unroll
  for (int mi = 0; mi < 4; ++mi) {
    #pragma unroll
    for (int ni = 0; ni < 4; ++ni) {
      int row = m0 + w * 64 + mi * 16 + lg * 4;
      int col = n0 + ni * 16 + lm;
      float bv_ = bias[col];
      #pragma unroll
      for (int j = 0; j < 4; ++j) {
        float o = acc[mi][ni][j] + bv_;
        if constexpr (RESMODE == 1)
          o += ((const float*)resv)[(size_t)(row + j) * N + col];
        if constexpr (RESMODE == 2)
          o += (float)((const bf16*)resv)[(size_t)(row + j) * N + col];
        if constexpr (GELU) {
          float z = 1.5957691216057308f * (o + 0.044715f * o * o * o);
          o = o / (1.0f + __expf(-z));
        }
        if constexpr (OUTF32)
          ((float*)outv)[(size_t)(row + j) * N + col] = o;
        else
          ((bf16*)outv)[(size_t)(row + j) * N + col] = (bf16)o;
      }
    }
  }
}

// ---------------- windowed attention (both branches) ------------------------
__global__ __launch_bounds__(256) void k_attn(
    const bf16* __restrict__ qkv,
    const float* __restrict__ rpb1, const float* __restrict__ rpb2,
    bf16* __restrict__ aout) {
  __shared__ bf16 vt[128 * 72];   // V^T: [channel][token(+pad)]
  __shared__ float rl[960];       // rpb: [h][dy][dx] stride 240/16/1

  int tid = threadIdx.x;
  int bx = blockIdx.x;
  int br = bx & 1, widx = (bx >> 1) & 63, b = bx >> 7;
  int wy = widx >> 3, wx = widx & 7;

  const float* rpb = br ? rpb2 : rpb1;
  #pragma unroll
  for (int t = tid; t < 960; t += 256) {
    int h0 = t / 240, r0 = t - h0 * 240, dy = r0 >> 4, dx = r0 & 15;
    rl[t] = (dx < 15) ? rpb[(dy * 15 + dx) * 4 + h0] : 0.f;
  }

  auto grow = [&](int tok) -> int {
    int y = wy * 8 + (tok >> 3), xc = wx * 8 + (tok & 7);
    if (br) { y = (y + 4) & 63; xc = (xc + 4) & 63; }
    return b * 4096 + y * 64 + xc;
  };

  // stage V transposed
  #pragma unroll
  for (int it = 0; it < 4; ++it) {
    int task = it * 256 + tid;
    int tok = task & 63, chunk = task >> 6;
    bf16x8v v = *(const bf16x8v*)&qkv[(size_t)grow(tok) * 768 + 512 + br * 128 + chunk * 8];
    #pragma unroll
    for (int u = 0; u < 8; ++u) vt[(chunk * 8 + u) * 72 + tok] = v[u];
  }

  int l = tid & 63, h = tid >> 6;
  int lm = l & 15, lg = l >> 4;

  bf16x8v kb[4], qa[4];
  #pragma unroll
  for (int i = 0; i < 4; ++i) {
    size_t rb = (size_t)grow(i * 16 + lm) * 768 + br * 128 + h * 32 + lg * 8;
    qa[i] = *(const bf16x8v*)&qkv[rb];
    kb[i] = *(const bf16x8v*)&qkv[rb + 256];
  }
  __syncthreads();   // vt + rl ready

  bf16x4v vb[2][4];
  #pragma unroll
  for (int ni = 0; ni < 2; ++ni)
    #pragma unroll
    for (int ki = 0; ki < 4; ++ki)
      vb[ni][ki] = *(const bf16x4v*)&vt[(h * 32 + ni * 16 + lm) * 72 + ki * 16 + lg * 4];

  bool need_mask = br && (wy == 7 || wx == 7);

  int ekA[16], idkA[16];
  #pragma unroll
  for (int ki = 0; ki < 4; ++ki)
    #pragma unroll
    for (int j = 0; j < 4; ++j) {
      int ik = ki * 16 + lg * 4 + j;
      ekA[ki * 4 + j] = ik + (ik >> 3) * 8;
      int yk = wy * 8 + (ik >> 3), xk = wx * 8 + (ik & 7);
      idkA[ki * 4 + j] = (yk < 56 ? 0 : (yk < 60 ? 1 : 2)) * 3
                       + (xk < 56 ? 0 : (xk < 60 ? 1 : 2));
    }

  #pragma unroll
  for (int qi = 0; qi < 4; ++qi) {
    f32x4 s[4];
    #pragma unroll
    for (int ki = 0; ki < 4; ++ki)
      s[ki] = mfma16(kb[ki], qa[qi], (f32x4){0.f,0.f,0.f,0.f});

    int iq = qi * 16 + lm;
    int eq = iq + (iq >> 3) * 8;
    int yq = wy * 8 + (iq >> 3), xq = wx * 8 + (iq & 7);
    int idq = (yq < 56 ? 0 : (yq < 60 ? 1 : 2)) * 3
            + (xq < 56 ? 0 : (xq < 60 ? 1 : 2));
    const float* fb = &rl[h * 240 + 119 + eq];

    #pragma unroll
    for (int ki = 0; ki < 4; ++ki)
      #pragma unroll
      for (int j = 0; j < 4; ++j) {
        float val = s[ki][j] * 0.17677669529663687f + fb[-ekA[ki * 4 + j]];
        if (need_mask && idq != idkA[ki * 4 + j]) val -= 100.0f;
        s[ki][j] = val;
      }

    float mx = s[0][0];
    #pragma unroll
    for (int ki = 0; ki < 4; ++ki)
      #pragma unroll
      for (int j = 0; j < 4; ++j) mx = fmaxf(mx, s[ki][j]);
    mx = fmaxf(mx, __shfl_xor(mx, 16));
    mx = fmaxf(mx, __shfl_xor(mx, 32));
    float sum = 0.f;
    #pragma unroll
    for (int ki = 0; ki < 4; ++ki)
      #pragma unroll
      for (int j = 0; j < 4; ++j) {
        float e = __expf(s[ki][j] - mx);
        s[ki][j] = e;
        sum += e;
      }
    sum += __shfl_xor(sum, 16);
    sum += __shfl_xor(sum, 32);
    float rs = 1.0f / sum;

    bf16x4v pa[4];
    #pragma unroll
    for (int ki = 0; ki < 4; ++ki)
      #pragma unroll
      for (int j = 0; j < 4; ++j)
        pa[ki][j] = (bf16)(s[ki][j] * rs);

    f32x4 o[2] = {(f32x4){0.f,0.f,0.f,0.f}, (f32x4){0.f,0.f,0.f,0.f}};
    #pragma unroll
    for (int ki = 0; ki < 4; ++ki) {
      o[0] = mfma16x16(pa[ki], vb[0][ki], o[0]);
      o[1] = mfma16x16(pa[ki], vb[1][ki], o[1]);
    }

    #pragma unroll
    for (int ni = 0; ni < 2; ++ni)
      #pragma unroll
      for (int j = 0; j < 4; ++j) {
        int tok = qi * 16 + lg * 4 + j;
        int col = br * 128 + h * 32 + ni * 16 + lm;
        aout[(size_t)grow(tok) * 256 + col] = (bf16)o[ni][j];
      }
  }
}

// ---------------- host ------------------------------------------------------
extern "C" void kernel_launch(void* const* d_in, const int* in_sizes, int n_in,
                              void* d_out, int out_size, void* d_ws, size_t ws_size,
                              hipStream_t stream) {
  (void)in_sizes; (void)n_in; (void)out_size; (void)ws_size;
  const float* x      = (const float*)d_in[0];
  const float* style  = (const float*)d_in[1];
  const float* w_qkv  = (const float*)d_in[2];
  const float* b_qkv  = (const float*)d_in[3];
  const float* w_proj = (const float*)d_in[4];
  const float* b_proj = (const float*)d_in[5];
  const float* w_ada1 = (const float*)d_in[6];
  const float* b_ada1 = (const float*)d_in[7];
  const float* w_ada2 = (const float*)d_in[8];
  const float* b_ada2 = (const float*)d_in[9];
  const float* rpb1   = (const float*)d_in[10];
  const float* rpb2   = (const float*)d_in[11];
  const float* w_fc1  = (const float*)d_in[12];
  const float* b_fc1  = (const float*)d_in[13];
  const float* w_fc2  = (const float*)d_in[14];
  const float* b_fc2  = (const float*)d_in[15];

  char* ws = (char*)d_ws;
  float* s1     = (float*)(ws + 0);
  float* s2     = (float*)(ws + 32768);
  float* scale1 = (float*)(ws + 65536);
  float* shift1 = (float*)(ws + 81920);
  float* scale2 = (float*)(ws + 98304);
  float* shift2 = (float*)(ws + 114688);
  bf16* wtqkv   = (bf16*)(ws + 131072);            // 768x256 bf16
  bf16* wtproj  = (bf16*)(ws + 524288);            // 256x256
  bf16* wtfc1   = (bf16*)(ws + 655360);            // 1024x256
  bf16* wtfc2   = (bf16*)(ws + 1179648);           // 256x1024
  float* psum   = (float*)(ws + 1703936);          // 16*16*256 f32
  float* psq    = (float*)(ws + 1966080);
  const size_t BIG = 2228224;
  bf16* xn   = (bf16*)(ws + BIG);                  // 65536x256 bf16 (33.5MB)
  bf16* qkv  = (bf16*)(ws + BIG + 33554432);       // 65536x768 bf16 (100.7MB)
  bf16* attn = (bf16*)(ws + BIG + 134217728);      // 65536x256 bf16 (33.5MB)
  bf16* x1   = (bf16*)(ws + BIG + 33554432);       // overlays qkv head
  bf16* xn2  = xn;                                 // reuses xn slot
  bf16* g    = (bf16*)(ws + BIG + 67108864);       // 32768x1024 chunk, qkv tail

  // weight transposes (f32 -> bf16)
  k_tr<<<dim3(24, 8),  256, 0, stream>>>(w_qkv,  wtqkv,  256, 768);
  k_tr<<<dim3(8, 8),   256, 0, stream>>>(w_proj, wtproj, 256, 256);
  k_tr<<<dim3(32, 8),  256, 0, stream>>>(w_fc1,  wtfc1,  256, 1024);
  k_tr<<<dim3(8, 32),  256, 0, stream>>>(w_fc2,  wtfc2,  1024, 256);

  // style projections, adain1 params, adain1 apply
  k_style<<<1024, 256, 0, stream>>>(style, w_ada1, b_ada1, w_ada2, b_ada2, s1, s2);
  k_stats_part<1><<<dim3(16, 16), 256, 0, stream>>>(x, psum, psq);
  k_stats_fin<<<16, 256, 0, stream>>>(psum, psq, s1, scale1, shift1);
  k_adain<1><<<8192, 256, 0, stream>>>(x, scale1, shift1, xn);

  // qkv = xn @ w_qkv + b_qkv          (256x64 tiles: 256 x 12 = 3072)
  k_gemm_stream<0,0,0><<<3072, 256, 0, stream>>>(
      xn, wtqkv, b_qkv, nullptr, qkv, 768, 256, 12);

  // windowed attention (both branches)
  k_attn<<<2048, 256, 0, stream>>>(qkv, rpb1, rpb2, attn);

  // x1 = x + attn @ w_proj + b_proj   (256 x 4 = 1024)
  k_gemm_stream<1,0,0><<<1024, 256, 0, stream>>>(
      attn, wtproj, b_proj, x, x1, 256, 256, 4);

  // adain2 params + apply
  k_stats_part<0><<<dim3(16, 16), 256, 0, stream>>>(x1, psum, psq);
  k_stats_fin<<<16, 256, 0, stream>>>(psum, psq, s2, scale2, shift2);
  k_adain<0><<<8192, 256, 0, stream>>>(x1, scale2, shift2, xn2);

  // MLP in 2 row-chunks of 32768 (g reuses dead qkv tail region)
  for (int ch = 0; ch < 2; ++ch) {
    size_t ro = (size_t)ch * 32768;
    // g = gelu(xn2 @ w_fc1 + b_fc1)   (128 x 16 = 2048)
    k_gemm_stream<0,1,0><<<2048, 256, 0, stream>>>(
        xn2 + ro * 256, wtfc1, b_fc1, nullptr, g, 1024, 256, 16);
    // out = x1 + g @ w_fc2 + b_fc2    (128 x 4 = 512; K=1024 -> 4 B-slabs)
    k_gemm_stream<2,0,1><<<512, 256, 0, stream>>>(
        g, wtfc2, b_fc2, x1 + ro * 256,
        (float*)d_out + ro * 256, 256, 1024, 4);
  }
}

// Round 12
// 326.279 us; speedup vs baseline: 1.3363x; 1.3363x over previous
//
#include <hip/hip_runtime.h>
#include <hip/hip_bf16.h>

typedef __bf16 bf16;
typedef __bf16 bf16x4v __attribute__((ext_vector_type(4)));
typedef __bf16 bf16x8v __attribute__((ext_vector_type(8)));
typedef float f32x4 __attribute__((ext_vector_type(4)));
typedef short s16x4 __attribute__((ext_vector_type(4)));

#define DEVINL static __device__ __forceinline__
#define AS1 __attribute__((address_space(1)))
#define AS3 __attribute__((address_space(3)))

DEVINL f32x4 mfma16(bf16x8v a, bf16x8v b, f32x4 c) {
  return __builtin_amdgcn_mfma_f32_16x16x32_bf16(a, b, c, 0, 0, 0);
}

DEVINL f32x4 mfma16x16(bf16x4v a, bf16x4v b, f32x4 c) {
#if __has_builtin(__builtin_amdgcn_mfma_f32_16x16x16bf16_1k)
  return __builtin_amdgcn_mfma_f32_16x16x16bf16_1k(
      __builtin_bit_cast(s16x4, a), __builtin_bit_cast(s16x4, b), c, 0, 0, 0);
#else
  f32x4 d;
  asm("v_mfma_f32_16x16x16_bf16 %0, %1, %2, %3"
      : "=v"(d) : "v"(a), "v"(b), "v"(c));
  return d;
#endif
}

// ---------------- style projections: s = style @ w_ada + b_ada (f32) --------
__global__ __launch_bounds__(256) void k_style(
    const float* __restrict__ style,
    const float* __restrict__ wa1, const float* __restrict__ ba1,
    const float* __restrict__ wa2, const float* __restrict__ ba2,
    float* __restrict__ s1, float* __restrict__ s2) {
  int bid = blockIdx.x;
  int ng = bid & 31, b = (bid >> 5) & 15, which = bid >> 9;
  int tid = threadIdx.x;
  int nl = tid & 15, kg = tid >> 4;
  int n = ng * 16 + nl;
  const float* wa = which ? wa2 : wa1;
  const float* ba = which ? ba2 : ba1;
  const float* srow = style + b * 512;
  float acc = 0.f;
  #pragma unroll 8
  for (int kk = 0; kk < 32; ++kk) {
    int k = kg + kk * 16;
    acc += srow[k] * wa[k * 512 + n];
  }
  acc += __shfl_xor(acc, 16);
  acc += __shfl_xor(acc, 32);
  __shared__ float red[4][16];
  int l = tid & 63, w = tid >> 6;
  if (l < 16) red[w][nl] = acc;
  __syncthreads();
  if (tid < 16) {
    float S = red[0][tid] + red[1][tid] + red[2][tid] + red[3][tid]
            + ba[ng * 16 + tid];
    (which ? s2 : s1)[b * 512 + ng * 16 + tid] = S;
  }
}

// ---------------- stats pass 1: per (b, row-chunk) partial sum/sumsq --------
template<int F32>
__global__ __launch_bounds__(256) void k_stats_part(
    const void* __restrict__ xv, float* __restrict__ psum,
    float* __restrict__ psq) {
  int rc = blockIdx.x, b = blockIdx.y;
  int c = threadIdx.x;
  size_t base = (size_t)b * 4096 * 256 + (size_t)rc * 256 * 256 + c;
  float sm = 0.f, q = 0.f;
  #pragma unroll 4
  for (int r = 0; r < 256; ++r) {
    float f;
    if constexpr (F32) f = ((const float*)xv)[base + (size_t)r * 256];
    else               f = (float)((const bf16*)xv)[base + (size_t)r * 256];
    sm += f; q += f * f;
  }
  int o = (b * 16 + rc) * 256 + c;
  psum[o] = sm; psq[o] = q;
}

// ---------------- stats pass 2: combine + adain scale/shift -----------------
__global__ __launch_bounds__(256) void k_stats_fin(
    const float* __restrict__ psum, const float* __restrict__ psq,
    const float* __restrict__ s,
    float* __restrict__ scale, float* __restrict__ shift) {
  int b = blockIdx.x, c = threadIdx.x;
  float S = 0.f, Q = 0.f;
  #pragma unroll
  for (int rc = 0; rc < 16; ++rc) {
    S += psum[(b * 16 + rc) * 256 + c];
    Q += psq[(b * 16 + rc) * 256 + c];
  }
  float mean = S * (1.0f/4096.0f);
  float var  = Q * (1.0f/4096.0f) - mean * mean;
  float inv  = rsqrtf(var + 1e-5f);
  float mu_s  = s[b * 512 + c];
  float std_s = s[b * 512 + 256 + c];
  float sc = std_s * inv;
  scale[b * 256 + c] = sc;
  shift[b * 256 + c] = mu_s - sc * mean;
}

// ---------------- adain apply: out_bf16 = shift + scale * in ----------------
template<int F32>
__global__ __launch_bounds__(256) void k_adain(
    const void* __restrict__ in, const float* __restrict__ scale,
    const float* __restrict__ shift, bf16* __restrict__ out) {
  int idx = blockIdx.x * 256 + threadIdx.x;
  int c8 = idx & 31, row = idx >> 5;
  int b = row >> 12, c = c8 * 8;
  const float* scp = &scale[b * 256 + c];
  const float* shp = &shift[b * 256 + c];
  f32x4 sc0 = *(const f32x4*)scp, sc1 = *(const f32x4*)(scp + 4);
  f32x4 sh0 = *(const f32x4*)shp, sh1 = *(const f32x4*)(shp + 4);
  size_t ofs = (size_t)row * 256 + c;
  float f[8];
  if constexpr (F32) {
    f32x4 v0 = *(const f32x4*)&((const float*)in)[ofs];
    f32x4 v1 = *(const f32x4*)&((const float*)in)[ofs + 4];
    f[0]=v0[0]; f[1]=v0[1]; f[2]=v0[2]; f[3]=v0[3];
    f[4]=v1[0]; f[5]=v1[1]; f[6]=v1[2]; f[7]=v1[3];
  } else {
    bf16x8v v = *(const bf16x8v*)&((const bf16*)in)[ofs];
    #pragma unroll
    for (int u = 0; u < 8; ++u) f[u] = (float)v[u];
  }
  bf16x8v o;
  o[0]=(bf16)(sh0[0]+sc0[0]*f[0]); o[1]=(bf16)(sh0[1]+sc0[1]*f[1]);
  o[2]=(bf16)(sh0[2]+sc0[2]*f[2]); o[3]=(bf16)(sh0[3]+sc0[3]*f[3]);
  o[4]=(bf16)(sh1[0]+sc1[0]*f[4]); o[5]=(bf16)(sh1[1]+sc1[1]*f[5]);
  o[6]=(bf16)(sh1[2]+sc1[2]*f[6]); o[7]=(bf16)(sh1[3]+sc1[3]*f[7]);
  *(bf16x8v*)&out[ofs] = o;
}

// ---------------- weight transpose+cvt (K x N f32) -> (N x K bf16) ----------
__global__ __launch_bounds__(256) void k_tr(
    const float* __restrict__ in, bf16* __restrict__ out, int K, int N) {
  __shared__ float t[32][33];
  int bx = blockIdx.x * 32, by = blockIdx.y * 32;
  int tx = threadIdx.x & 31, ty = threadIdx.x >> 5;
  #pragma unroll
  for (int r = 0; r < 32; r += 8)
    t[ty + r][tx] = in[(size_t)(by + ty + r) * N + bx + tx];
  __syncthreads();
  #pragma unroll
  for (int r = 0; r < 32; r += 8)
    out[(size_t)(bx + ty + r) * K + by + tx] = (bf16)t[tx][ty + r];
}

// ---------------- GEMM (8-wave 256x128, r10 proven): out = A@Bt^T + ... -----
template<int RESMODE, int GELU, int OUTF32>
__global__ __launch_bounds__(512) void k_gemm(
    const bf16* __restrict__ A, const bf16* __restrict__ Bt,
    const float* __restrict__ bias, const void* __restrict__ resv,
    void* __restrict__ outv, int N, int K, int gx) {
  __shared__ bf16 a_sw[256 * 64];   // 32 KB
  __shared__ bf16 b_sw[128 * 64];   // 16 KB
  int tid = threadIdx.x;
  int l = tid & 63, w = tid >> 6;
  int wr = w >> 1, wc = w & 1;             // 4x2 waves, 64x64 each
  int lm = l & 15, lg = l >> 4;

  int nwg = gridDim.x;
  int lin = blockIdx.x;
  int swz = (lin & 7) * (nwg >> 3) + (lin >> 3);
  int bx = swz % gx, by = swz / gx;
  int m0 = by * 256, n0 = bx * 128;

  f32x4 acc[4][4];
  #pragma unroll
  for (int mi = 0; mi < 4; ++mi)
    #pragma unroll
    for (int ni = 0; ni < 4; ++ni)
      acc[mi][ni] = (f32x4){0.f, 0.f, 0.f, 0.f};

  for (int k0 = 0; k0 < K; k0 += 64) {
    #pragma unroll
    for (int i = 0; i < 4; ++i) {
      int slot = i * 512 + tid;
      int r = slot >> 3, cs = slot & 7;
      int c = cs ^ (r & 7);                // inverse swizzle on SOURCE
      const bf16* g = A + (size_t)(m0 + r) * K + k0 + c * 8;
      __builtin_amdgcn_global_load_lds(
          (const AS1 void*)g, (AS3 void*)(a_sw + (i * 512 + w * 64) * 8),
          16, 0, 0);
    }
    #pragma unroll
    for (int i = 0; i < 2; ++i) {
      int slot = i * 512 + tid;
      int r = slot >> 3, cs = slot & 7;
      int c = cs ^ (r & 7);
      const bf16* g = Bt + (size_t)(n0 + r) * K + k0 + c * 8;
      __builtin_amdgcn_global_load_lds(
          (const AS1 void*)g, (AS3 void*)(b_sw + (i * 512 + w * 64) * 8),
          16, 0, 0);
    }
    __syncthreads();
    #pragma unroll
    for (int kk = 0; kk < 2; ++kk) {
      bf16x8v af[4], bv[4];
      #pragma unroll
      for (int mi = 0; mi < 4; ++mi) {
        int row = wr * 64 + mi * 16 + lm;
        af[mi] = *(const bf16x8v*)&a_sw[row * 64 + (((kk * 4 + lg) ^ (row & 7)) * 8)];
      }
      #pragma unroll
      for (int ni = 0; ni < 4; ++ni) {
        int row = wc * 64 + ni * 16 + lm;
        bv[ni] = *(const bf16x8v*)&b_sw[row * 64 + (((kk * 4 + lg) ^ (row & 7)) * 8)];
      }
      #pragma unroll
      for (int mi = 0; mi < 4; ++mi)
        #pragma unroll
        for (int ni = 0; ni < 4; ++ni)
          acc[mi][ni] = mfma16(af[mi], bv[ni], acc[mi][ni]);
    }
    __syncthreads();
  }
  #pragma unroll
  for (int mi = 0; mi < 4; ++mi) {
    #pragma unroll
    for (int ni = 0; ni < 4; ++ni) {
      int row = m0 + wr * 64 + mi * 16 + lg * 4;
      int col = n0 + wc * 64 + ni * 16 + lm;
      float bv_ = bias[col];
      #pragma unroll
      for (int j = 0; j < 4; ++j) {
        float o = acc[mi][ni][j] + bv_;
        if constexpr (RESMODE == 1)
          o += ((const float*)resv)[(size_t)(row + j) * N + col];
        if constexpr (RESMODE == 2)
          o += (float)((const bf16*)resv)[(size_t)(row + j) * N + col];
        if constexpr (GELU) {
          float z = 1.5957691216057308f * (o + 0.044715f * o * o * o);
          o = o / (1.0f + __expf(-z));
        }
        if constexpr (OUTF32)
          ((float*)outv)[(size_t)(row + j) * N + col] = o;
        else
          ((bf16*)outv)[(size_t)(row + j) * N + col] = (bf16)o;
      }
    }
  }
}

// ---------------- GEMM (4-wave 128x128, r7 proven) — for small grids --------
template<int RESMODE, int GELU, int OUTF32>
__global__ __launch_bounds__(256) void k_gemm4(
    const bf16* __restrict__ A, const bf16* __restrict__ Bt,
    const float* __restrict__ bias, const void* __restrict__ resv,
    void* __restrict__ outv, int N, int K, int gx) {
  __shared__ bf16 a_sw[128 * 64];
  __shared__ bf16 b_sw[128 * 64];
  int tid = threadIdx.x;
  int l = tid & 63, w = tid >> 6;
  int wr = w >> 1, wc = w & 1;
  int lm = l & 15, lg = l >> 4;

  int nwg = gridDim.x;
  int lin = blockIdx.x;
  int swz = (lin & 7) * (nwg >> 3) + (lin >> 3);
  int bx = swz % gx, by = swz / gx;
  int m0 = by * 128, n0 = bx * 128;

  f32x4 acc[4][4];
  #pragma unroll
  for (int mi = 0; mi < 4; ++mi)
    #pragma unroll
    for (int ni = 0; ni < 4; ++ni)
      acc[mi][ni] = (f32x4){0.f, 0.f, 0.f, 0.f};

  for (int k0 = 0; k0 < K; k0 += 64) {
    #pragma unroll
    for (int i = 0; i < 4; ++i) {
      int slot = i * 256 + tid;
      int r = slot >> 3, cs = slot & 7;
      int c = cs ^ (r & 7);
      __builtin_amdgcn_global_load_lds(
          (const AS1 void*)(A + (size_t)(m0 + r) * K + k0 + c * 8),
          (AS3 void*)(a_sw + (i * 256 + w * 64) * 8), 16, 0, 0);
    }
    #pragma unroll
    for (int i = 0; i < 4; ++i) {
      int slot = i * 256 + tid;
      int r = slot >> 3, cs = slot & 7;
      int c = cs ^ (r & 7);
      __builtin_amdgcn_global_load_lds(
          (const AS1 void*)(Bt + (size_t)(n0 + r) * K + k0 + c * 8),
          (AS3 void*)(b_sw + (i * 256 + w * 64) * 8), 16, 0, 0);
    }
    __syncthreads();
    #pragma unroll
    for (int kk = 0; kk < 2; ++kk) {
      bf16x8v af[4], bv[4];
      #pragma unroll
      for (int mi = 0; mi < 4; ++mi) {
        int row = wr * 64 + mi * 16 + lm;
        af[mi] = *(const bf16x8v*)&a_sw[row * 64 + (((kk * 4 + lg) ^ (row & 7)) * 8)];
      }
      #pragma unroll
      for (int ni = 0; ni < 4; ++ni) {
        int row = wc * 64 + ni * 16 + lm;
        bv[ni] = *(const bf16x8v*)&b_sw[row * 64 + (((kk * 4 + lg) ^ (row & 7)) * 8)];
      }
      #pragma unroll
      for (int mi = 0; mi < 4; ++mi)
        #pragma unroll
        for (int ni = 0; ni < 4; ++ni)
          acc[mi][ni] = mfma16(af[mi], bv[ni], acc[mi][ni]);
    }
    __syncthreads();
  }
  #pragma unroll
  for (int mi = 0; mi < 4; ++mi) {
    #pragma unroll
    for (int ni = 0; ni < 4; ++ni) {
      int row = m0 + wr * 64 + mi * 16 + lg * 4;
      int col = n0 + wc * 64 + ni * 16 + lm;
      float bv_ = bias[col];
      #pragma unroll
      for (int j = 0; j < 4; ++j) {
        float o = acc[mi][ni][j] + bv_;
        if constexpr (RESMODE == 1)
          o += ((const float*)resv)[(size_t)(row + j) * N + col];
        if constexpr (RESMODE == 2)
          o += (float)((const bf16*)resv)[(size_t)(row + j) * N + col];
        if constexpr (GELU) {
          float z = 1.5957691216057308f * (o + 0.044715f * o * o * o);
          o = o / (1.0f + __expf(-z));
        }
        if constexpr (OUTF32)
          ((float*)outv)[(size_t)(row + j) * N + col] = o;
        else
          ((bf16*)outv)[(size_t)(row + j) * N + col] = (bf16)o;
      }
    }
  }
}

// ---------------- windowed attention (both branches) ------------------------
// block = (b, window, branch); 4 waves = 4 heads (d=32), 64 tokens.
// V staged coalesced (16 lanes = 256B contiguous) into swizzled V^T:
// vt[ch*72 + (tok ^ ((ch>>3)&7)<<3)] — same XOR on PV read (involution).
__global__ __launch_bounds__(256) void k_attn(
    const bf16* __restrict__ qkv,
    const float* __restrict__ rpb1, const float* __restrict__ rpb2,
    bf16* __restrict__ aout) {
  __shared__ bf16 vt[128 * 72];   // V^T: [channel][token-swizzled(+pad)]
  __shared__ float rl[960];       // rpb: [h][dy][dx] stride 240/16/1

  int tid = threadIdx.x;
  int bx = blockIdx.x;
  int br = bx & 1, widx = (bx >> 1) & 63, b = bx >> 7;
  int wy = widx >> 3, wx = widx & 7;

  const float* rpb = br ? rpb2 : rpb1;
  #pragma unroll
  for (int t = tid; t < 960; t += 256) {
    int h0 = t / 240, r0 = t - h0 * 240, dy = r0 >> 4, dx = r0 & 15;
    rl[t] = (dx < 15) ? rpb[(dy * 15 + dx) * 4 + h0] : 0.f;
  }

  auto grow = [&](int tok) -> int {
    int y = wy * 8 + (tok >> 3), xc = wx * 8 + (tok & 7);
    if (br) { y = (y + 4) & 63; xc = (xc + 4) & 63; }
    return b * 4096 + y * 64 + xc;
  };

  // stage V transposed: task = tok*16 + chunk -> 16 lanes read 256B contiguous
  #pragma unroll
  for (int it = 0; it < 4; ++it) {
    int task = it * 256 + tid;
    int tok = task >> 4, chunk = task & 15;
    bf16x8v v = *(const bf16x8v*)&qkv[(size_t)grow(tok) * 768 + 512 + br * 128 + chunk * 8];
    int tsw = tok ^ ((chunk & 7) << 3);     // bank-spread swizzle
    #pragma unroll
    for (int u = 0; u < 8; ++u) vt[(chunk * 8 + u) * 72 + tsw] = v[u];
  }

  int l = tid & 63, h = tid >> 6;
  int lm = l & 15, lg = l >> 4;

  // K frags (A-operand, rows = k-tokens) and Q frags (B-operand, cols = q)
  bf16x8v kb[4], qa[4];
  #pragma unroll
  for (int i = 0; i < 4; ++i) {
    size_t rb = (size_t)grow(i * 16 + lm) * 768 + br * 128 + h * 32 + lg * 8;
    qa[i] = *(const bf16x8v*)&qkv[rb];
    kb[i] = *(const bf16x8v*)&qkv[rb + 256];
  }
  __syncthreads();   // vt + rl ready

  // V B-frags for 16x16x16 PV: row=ch, col block tok = ki*16+lg*4 (+u in low bits)
  bf16x4v vb[2][4];
  #pragma unroll
  for (int ni = 0; ni < 2; ++ni)
    #pragma unroll
    for (int ki = 0; ki < 4; ++ki) {
      int row = h * 32 + ni * 16 + lm;
      int col = (ki * 16 + lg * 4) ^ (((row >> 3) & 7) << 3);
      vb[ni][ki] = *(const bf16x4v*)&vt[row * 72 + col];
    }

  bool need_mask = br && (wy == 7 || wx == 7);

  int ekA[16], idkA[16];
  #pragma unroll
  for (int ki = 0; ki < 4; ++ki)
    #pragma unroll
    for (int j = 0; j < 4; ++j) {
      int ik = ki * 16 + lg * 4 + j;
      ekA[ki * 4 + j] = ik + (ik >> 3) * 8;
      int yk = wy * 8 + (ik >> 3), xk = wx * 8 + (ik & 7);
      idkA[ki * 4 + j] = (yk < 56 ? 0 : (yk < 60 ? 1 : 2)) * 3
                       + (xk < 56 ? 0 : (xk < 60 ? 1 : 2));
    }

  #pragma unroll
  for (int qi = 0; qi < 4; ++qi) {
    f32x4 s[4];
    #pragma unroll
    for (int ki = 0; ki < 4; ++ki)
      s[ki] = mfma16(kb[ki], qa[qi], (f32x4){0.f,0.f,0.f,0.f});

    int iq = qi * 16 + lm;
    int eq = iq + (iq >> 3) * 8;
    int yq = wy * 8 + (iq >> 3), xq = wx * 8 + (iq & 7);
    int idq = (yq < 56 ? 0 : (yq < 60 ? 1 : 2)) * 3
            + (xq < 56 ? 0 : (xq < 60 ? 1 : 2));
    const float* fb = &rl[h * 240 + 119 + eq];

    #pragma unroll
    for (int ki = 0; ki < 4; ++ki)
      #pragma unroll
      for (int j = 0; j < 4; ++j) {
        float val = s[ki][j] * 0.17677669529663687f + fb[-ekA[ki * 4 + j]];
        if (need_mask && idq != idkA[ki * 4 + j]) val -= 100.0f;
        s[ki][j] = val;
      }

    float mx = s[0][0];
    #pragma unroll
    for (int ki = 0; ki < 4; ++ki)
      #pragma unroll
      for (int j = 0; j < 4; ++j) mx = fmaxf(mx, s[ki][j]);
    mx = fmaxf(mx, __shfl_xor(mx, 16));
    mx = fmaxf(mx, __shfl_xor(mx, 32));
    float sum = 0.f;
    #pragma unroll
    for (int ki = 0; ki < 4; ++ki)
      #pragma unroll
      for (int j = 0; j < 4; ++j) {
        float e = __expf(s[ki][j] - mx);
        s[ki][j] = e;
        sum += e;
      }
    sum += __shfl_xor(sum, 16);
    sum += __shfl_xor(sum, 32);
    float rs = 1.0f / sum;

    bf16x4v pa[4];
    #pragma unroll
    for (int ki = 0; ki < 4; ++ki)
      #pragma unroll
      for (int j = 0; j < 4; ++j)
        pa[ki][j] = (bf16)(s[ki][j] * rs);

    f32x4 o[2] = {(f32x4){0.f,0.f,0.f,0.f}, (f32x4){0.f,0.f,0.f,0.f}};
    #pragma unroll
    for (int ki = 0; ki < 4; ++ki) {
      o[0] = mfma16x16(pa[ki], vb[0][ki], o[0]);
      o[1] = mfma16x16(pa[ki], vb[1][ki], o[1]);
    }

    #pragma unroll
    for (int ni = 0; ni < 2; ++ni)
      #pragma unroll
      for (int j = 0; j < 4; ++j) {
        int tok = qi * 16 + lg * 4 + j;
        int col = br * 128 + h * 32 + ni * 16 + lm;
        aout[(size_t)grow(tok) * 256 + col] = (bf16)o[ni][j];
      }
  }
}

// ---------------- host ------------------------------------------------------
extern "C" void kernel_launch(void* const* d_in, const int* in_sizes, int n_in,
                              void* d_out, int out_size, void* d_ws, size_t ws_size,
                              hipStream_t stream) {
  (void)in_sizes; (void)n_in; (void)out_size; (void)ws_size;
  const float* x      = (const float*)d_in[0];
  const float* style  = (const float*)d_in[1];
  const float* w_qkv  = (const float*)d_in[2];
  const float* b_qkv  = (const float*)d_in[3];
  const float* w_proj = (const float*)d_in[4];
  const float* b_proj = (const float*)d_in[5];
  const float* w_ada1 = (const float*)d_in[6];
  const float* b_ada1 = (const float*)d_in[7];
  const float* w_ada2 = (const float*)d_in[8];
  const float* b_ada2 = (const float*)d_in[9];
  const float* rpb1   = (const float*)d_in[10];
  const float* rpb2   = (const float*)d_in[11];
  const float* w_fc1  = (const float*)d_in[12];
  const float* b_fc1  = (const float*)d_in[13];
  const float* w_fc2  = (const float*)d_in[14];
  const float* b_fc2  = (const float*)d_in[15];

  char* ws = (char*)d_ws;
  float* s1     = (float*)(ws + 0);
  float* s2     = (float*)(ws + 32768);
  float* scale1 = (float*)(ws + 65536);
  float* shift1 = (float*)(ws + 81920);
  float* scale2 = (float*)(ws + 98304);
  float* shift2 = (float*)(ws + 114688);
  bf16* wtqkv   = (bf16*)(ws + 131072);            // 768x256 bf16
  bf16* wtproj  = (bf16*)(ws + 524288);            // 256x256
  bf16* wtfc1   = (bf16*)(ws + 655360);            // 1024x256
  bf16* wtfc2   = (bf16*)(ws + 1179648);           // 256x1024
  float* psum   = (float*)(ws + 1703936);          // 16*16*256 f32
  float* psq    = (float*)(ws + 1966080);
  const size_t BIG = 2228224;
  bf16* xn   = (bf16*)(ws + BIG);                  // 65536x256 bf16 (33.5MB)
  bf16* qkv  = (bf16*)(ws + BIG + 33554432);       // 65536x768 bf16 (100.7MB)
  bf16* attn = (bf16*)(ws + BIG + 134217728);      // 65536x256 bf16 (33.5MB)
  bf16* x1   = (bf16*)(ws + BIG + 33554432);       // overlays qkv head
  bf16* xn2  = xn;                                 // reuses xn slot
  bf16* g    = (bf16*)(ws + BIG + 67108864);       // 32768x1024 chunk, qkv tail

  // weight transposes (f32 -> bf16)
  k_tr<<<dim3(24, 8),  256, 0, stream>>>(w_qkv,  wtqkv,  256, 768);
  k_tr<<<dim3(8, 8),   256, 0, stream>>>(w_proj, wtproj, 256, 256);
  k_tr<<<dim3(32, 8),  256, 0, stream>>>(w_fc1,  wtfc1,  256, 1024);
  k_tr<<<dim3(8, 32),  256, 0, stream>>>(w_fc2,  wtfc2,  1024, 256);

  // style projections, adain1 params, adain1 apply
  k_style<<<1024, 256, 0, stream>>>(style, w_ada1, b_ada1, w_ada2, b_ada2, s1, s2);
  k_stats_part<1><<<dim3(16, 16), 256, 0, stream>>>(x, psum, psq);
  k_stats_fin<<<16, 256, 0, stream>>>(psum, psq, s1, scale1, shift1);
  k_adain<1><<<8192, 256, 0, stream>>>(x, scale1, shift1, xn);

  // qkv = xn @ w_qkv + b_qkv          (256x128 tiles: 256 x 6 = 1536)
  k_gemm<0,0,0><<<1536, 512, 0, stream>>>(
      xn, wtqkv, b_qkv, nullptr, qkv, 768, 256, 6);

  // windowed attention (both branches)
  k_attn<<<2048, 256, 0, stream>>>(qkv, rpb1, rpb2, attn);

  // x1 = x + attn @ w_proj + b_proj   (128x128: 512 x 2 = 1024)
  k_gemm4<1,0,0><<<1024, 256, 0, stream>>>(
      attn, wtproj, b_proj, x, x1, 256, 256, 2);

  // adain2 params + apply
  k_stats_part<0><<<dim3(16, 16), 256, 0, stream>>>(x1, psum, psq);
  k_stats_fin<<<16, 256, 0, stream>>>(psum, psq, s2, scale2, shift2);
  k_adain<0><<<8192, 256, 0, stream>>>(x1, scale2, shift2, xn2);

  // MLP in 2 row-chunks of 32768 (g reuses dead qkv tail region)
  for (int ch = 0; ch < 2; ++ch) {
    size_t ro = (size_t)ch * 32768;
    // g = gelu(xn2 @ w_fc1 + b_fc1)   (256x128: 128 x 8 = 1024)
    k_gemm<0,1,0><<<1024, 512, 0, stream>>>(
        xn2 + ro * 256, wtfc1, b_fc1, nullptr, g, 1024, 256, 8);
    // out = x1 + g @ w_fc2 + b_fc2    (128x128: 256 x 2 = 512)
    k_gemm4<2,0,1><<<512, 256, 0, stream>>>(
        g, wtfc2, b_fc2, x1 + ro * 256,
        (float*)d_out + ro * 256, 256, 1024, 2);
  }
}

// Round 13
// 321.999 us; speedup vs baseline: 1.3540x; 1.0133x over previous
//
#include <hip/hip_runtime.h>
#include <hip/hip_bf16.h>

typedef __bf16 bf16;
typedef __bf16 bf16x4v __attribute__((ext_vector_type(4)));
typedef __bf16 bf16x8v __attribute__((ext_vector_type(8)));
typedef float f32x4 __attribute__((ext_vector_type(4)));
typedef short s16x4 __attribute__((ext_vector_type(4)));

#define DEVINL static __device__ __forceinline__
#define AS1 __attribute__((address_space(1)))
#define AS3 __attribute__((address_space(3)))

DEVINL f32x4 mfma16(bf16x8v a, bf16x8v b, f32x4 c) {
  return __builtin_amdgcn_mfma_f32_16x16x32_bf16(a, b, c, 0, 0, 0);
}

DEVINL f32x4 mfma16x16(bf16x4v a, bf16x4v b, f32x4 c) {
#if __has_builtin(__builtin_amdgcn_mfma_f32_16x16x16bf16_1k)
  return __builtin_amdgcn_mfma_f32_16x16x16bf16_1k(
      __builtin_bit_cast(s16x4, a), __builtin_bit_cast(s16x4, b), c, 0, 0, 0);
#else
  f32x4 d;
  asm("v_mfma_f32_16x16x16_bf16 %0, %1, %2, %3"
      : "=v"(d) : "v"(a), "v"(b), "v"(c));
  return d;
#endif
}

// ---------------- style projections: s = style @ w_ada + b_ada (f32) --------
__global__ __launch_bounds__(256) void k_style(
    const float* __restrict__ style,
    const float* __restrict__ wa1, const float* __restrict__ ba1,
    const float* __restrict__ wa2, const float* __restrict__ ba2,
    float* __restrict__ s1, float* __restrict__ s2) {
  int bid = blockIdx.x;
  int ng = bid & 31, b = (bid >> 5) & 15, which = bid >> 9;
  int tid = threadIdx.x;
  int nl = tid & 15, kg = tid >> 4;
  int n = ng * 16 + nl;
  const float* wa = which ? wa2 : wa1;
  const float* ba = which ? ba2 : ba1;
  const float* srow = style + b * 512;
  float acc = 0.f;
  #pragma unroll 8
  for (int kk = 0; kk < 32; ++kk) {
    int k = kg + kk * 16;
    acc += srow[k] * wa[k * 512 + n];
  }
  acc += __shfl_xor(acc, 16);
  acc += __shfl_xor(acc, 32);
  __shared__ float red[4][16];
  int l = tid & 63, w = tid >> 6;
  if (l < 16) red[w][nl] = acc;
  __syncthreads();
  if (tid < 16) {
    float S = red[0][tid] + red[1][tid] + red[2][tid] + red[3][tid]
            + ba[ng * 16 + tid];
    (which ? s2 : s1)[b * 512 + ng * 16 + tid] = S;
  }
}

// ---------------- stats pass 1: per (b, row-chunk) partial sum/sumsq --------
template<int F32>
__global__ __launch_bounds__(256) void k_stats_part(
    const void* __restrict__ xv, float* __restrict__ psum,
    float* __restrict__ psq) {
  int rc = blockIdx.x, b = blockIdx.y;
  int c = threadIdx.x;
  size_t base = (size_t)b * 4096 * 256 + (size_t)rc * 256 * 256 + c;
  float sm = 0.f, q = 0.f;
  #pragma unroll 4
  for (int r = 0; r < 256; ++r) {
    float f;
    if constexpr (F32) f = ((const float*)xv)[base + (size_t)r * 256];
    else               f = (float)((const bf16*)xv)[base + (size_t)r * 256];
    sm += f; q += f * f;
  }
  int o = (b * 16 + rc) * 256 + c;
  psum[o] = sm; psq[o] = q;
}

// ---------------- stats pass 2: combine + adain scale/shift -----------------
__global__ __launch_bounds__(256) void k_stats_fin(
    const float* __restrict__ psum, const float* __restrict__ psq,
    const float* __restrict__ s,
    float* __restrict__ scale, float* __restrict__ shift) {
  int b = blockIdx.x, c = threadIdx.x;
  float S = 0.f, Q = 0.f;
  #pragma unroll
  for (int rc = 0; rc < 16; ++rc) {
    S += psum[(b * 16 + rc) * 256 + c];
    Q += psq[(b * 16 + rc) * 256 + c];
  }
  float mean = S * (1.0f/4096.0f);
  float var  = Q * (1.0f/4096.0f) - mean * mean;
  float inv  = rsqrtf(var + 1e-5f);
  float mu_s  = s[b * 512 + c];
  float std_s = s[b * 512 + 256 + c];
  float sc = std_s * inv;
  scale[b * 256 + c] = sc;
  shift[b * 256 + c] = mu_s - sc * mean;
}

// ---------------- adain apply: out_bf16 = shift + scale * in ----------------
template<int F32>
__global__ __launch_bounds__(256) void k_adain(
    const void* __restrict__ in, const float* __restrict__ scale,
    const float* __restrict__ shift, bf16* __restrict__ out) {
  int idx = blockIdx.x * 256 + threadIdx.x;
  int c8 = idx & 31, row = idx >> 5;
  int b = row >> 12, c = c8 * 8;
  const float* scp = &scale[b * 256 + c];
  const float* shp = &shift[b * 256 + c];
  f32x4 sc0 = *(const f32x4*)scp, sc1 = *(const f32x4*)(scp + 4);
  f32x4 sh0 = *(const f32x4*)shp, sh1 = *(const f32x4*)(shp + 4);
  size_t ofs = (size_t)row * 256 + c;
  float f[8];
  if constexpr (F32) {
    f32x4 v0 = *(const f32x4*)&((const float*)in)[ofs];
    f32x4 v1 = *(const f32x4*)&((const float*)in)[ofs + 4];
    f[0]=v0[0]; f[1]=v0[1]; f[2]=v0[2]; f[3]=v0[3];
    f[4]=v1[0]; f[5]=v1[1]; f[6]=v1[2]; f[7]=v1[3];
  } else {
    bf16x8v v = *(const bf16x8v*)&((const bf16*)in)[ofs];
    #pragma unroll
    for (int u = 0; u < 8; ++u) f[u] = (float)v[u];
  }
  bf16x8v o;
  o[0]=(bf16)(sh0[0]+sc0[0]*f[0]); o[1]=(bf16)(sh0[1]+sc0[1]*f[1]);
  o[2]=(bf16)(sh0[2]+sc0[2]*f[2]); o[3]=(bf16)(sh0[3]+sc0[3]*f[3]);
  o[4]=(bf16)(sh1[0]+sc1[0]*f[4]); o[5]=(bf16)(sh1[1]+sc1[1]*f[5]);
  o[6]=(bf16)(sh1[2]+sc1[2]*f[6]); o[7]=(bf16)(sh1[3]+sc1[3]*f[7]);
  *(bf16x8v*)&out[ofs] = o;
}

// ---------------- weight transpose+cvt (K x N f32) -> (N x K bf16) ----------
__global__ __launch_bounds__(256) void k_tr(
    const float* __restrict__ in, bf16* __restrict__ out, int K, int N) {
  __shared__ float t[32][33];
  int bx = blockIdx.x * 32, by = blockIdx.y * 32;
  int tx = threadIdx.x & 31, ty = threadIdx.x >> 5;
  #pragma unroll
  for (int r = 0; r < 32; r += 8)
    t[ty + r][tx] = in[(size_t)(by + ty + r) * N + bx + tx];
  __syncthreads();
  #pragma unroll
  for (int r = 0; r < 32; r += 8)
    out[(size_t)(bx + ty + r) * K + by + tx] = (bf16)t[tx][ty + r];
}

// ---------------- GEMM (8-wave 256x128): out = A@Bt^T + bias (+res,gelu) ----
// OUTMODE: 0 = bf16 row-major, 1 = f32 row-major,
//          2 = bf16 qkv-layout [(b*3+m)*8+hh][tok(4096)][32] (attention-native)
template<int RESMODE, int GELU, int OUTMODE>
__global__ __launch_bounds__(512) void k_gemm(
    const bf16* __restrict__ A, const bf16* __restrict__ Bt,
    const float* __restrict__ bias, const void* __restrict__ resv,
    void* __restrict__ outv, int N, int K, int gx) {
  __shared__ bf16 a_sw[256 * 64];   // 32 KB
  __shared__ bf16 b_sw[128 * 64];   // 16 KB
  int tid = threadIdx.x;
  int l = tid & 63, w = tid >> 6;
  int wr = w >> 1, wc = w & 1;             // 4x2 waves, 64x64 each
  int lm = l & 15, lg = l >> 4;

  int nwg = gridDim.x;
  int lin = blockIdx.x;
  int swz = (lin & 7) * (nwg >> 3) + (lin >> 3);
  int bx = swz % gx, by = swz / gx;
  int m0 = by * 256, n0 = bx * 128;

  f32x4 acc[4][4];
  #pragma unroll
  for (int mi = 0; mi < 4; ++mi)
    #pragma unroll
    for (int ni = 0; ni < 4; ++ni)
      acc[mi][ni] = (f32x4){0.f, 0.f, 0.f, 0.f};

  for (int k0 = 0; k0 < K; k0 += 64) {
    #pragma unroll
    for (int i = 0; i < 4; ++i) {
      int slot = i * 512 + tid;
      int r = slot >> 3, cs = slot & 7;
      int c = cs ^ (r & 7);                // inverse swizzle on SOURCE
      const bf16* g = A + (size_t)(m0 + r) * K + k0 + c * 8;
      __builtin_amdgcn_global_load_lds(
          (const AS1 void*)g, (AS3 void*)(a_sw + (i * 512 + w * 64) * 8),
          16, 0, 0);
    }
    #pragma unroll
    for (int i = 0; i < 2; ++i) {
      int slot = i * 512 + tid;
      int r = slot >> 3, cs = slot & 7;
      int c = cs ^ (r & 7);
      const bf16* g = Bt + (size_t)(n0 + r) * K + k0 + c * 8;
      __builtin_amdgcn_global_load_lds(
          (const AS1 void*)g, (AS3 void*)(b_sw + (i * 512 + w * 64) * 8),
          16, 0, 0);
    }
    __syncthreads();
    #pragma unroll
    for (int kk = 0; kk < 2; ++kk) {
      bf16x8v af[4], bv[4];
      #pragma unroll
      for (int mi = 0; mi < 4; ++mi) {
        int row = wr * 64 + mi * 16 + lm;
        af[mi] = *(const bf16x8v*)&a_sw[row * 64 + (((kk * 4 + lg) ^ (row & 7)) * 8)];
      }
      #pragma unroll
      for (int ni = 0; ni < 4; ++ni) {
        int row = wc * 64 + ni * 16 + lm;
        bv[ni] = *(const bf16x8v*)&b_sw[row * 64 + (((kk * 4 + lg) ^ (row & 7)) * 8)];
      }
      #pragma unroll
      for (int mi = 0; mi < 4; ++mi)
        #pragma unroll
        for (int ni = 0; ni < 4; ++ni)
          acc[mi][ni] = mfma16(af[mi], bv[ni], acc[mi][ni]);
    }
    __syncthreads();
  }
  #pragma unroll
  for (int mi = 0; mi < 4; ++mi) {
    #pragma unroll
    for (int ni = 0; ni < 4; ++ni) {
      int row = m0 + wr * 64 + mi * 16 + lg * 4;
      int col = n0 + wc * 64 + ni * 16 + lm;
      float bv_ = bias[col];
      #pragma unroll
      for (int j = 0; j < 4; ++j) {
        float o = acc[mi][ni][j] + bv_;
        if constexpr (RESMODE == 1)
          o += ((const float*)resv)[(size_t)(row + j) * N + col];
        if constexpr (RESMODE == 2)
          o += (float)((const bf16*)resv)[(size_t)(row + j) * N + col];
        if constexpr (GELU) {
          float z = 1.5957691216057308f * (o + 0.044715f * o * o * o);
          o = o / (1.0f + __expf(-z));
        }
        if constexpr (OUTMODE == 1)
          ((float*)outv)[(size_t)(row + j) * N + col] = o;
        else if constexpr (OUTMODE == 2) {
          int b  = (row + j) >> 12, tok = (row + j) & 4095;
          int m  = col >> 8, c2 = col & 255;
          int hh = c2 >> 5, ch = c2 & 31;
          size_t a_ = ((size_t)((b * 3 + m) * 8 + hh) << 17) + (tok << 5) + ch;
          ((bf16*)outv)[a_] = (bf16)o;
        } else
          ((bf16*)outv)[(size_t)(row + j) * N + col] = (bf16)o;
      }
    }
  }
}

// ---------------- GEMM (4-wave 128x128) — for small grids -------------------
template<int RESMODE, int GELU, int OUTF32>
__global__ __launch_bounds__(256) void k_gemm4(
    const bf16* __restrict__ A, const bf16* __restrict__ Bt,
    const float* __restrict__ bias, const void* __restrict__ resv,
    void* __restrict__ outv, int N, int K, int gx) {
  __shared__ bf16 a_sw[128 * 64];
  __shared__ bf16 b_sw[128 * 64];
  int tid = threadIdx.x;
  int l = tid & 63, w = tid >> 6;
  int wr = w >> 1, wc = w & 1;
  int lm = l & 15, lg = l >> 4;

  int nwg = gridDim.x;
  int lin = blockIdx.x;
  int swz = (lin & 7) * (nwg >> 3) + (lin >> 3);
  int bx = swz % gx, by = swz / gx;
  int m0 = by * 128, n0 = bx * 128;

  f32x4 acc[4][4];
  #pragma unroll
  for (int mi = 0; mi < 4; ++mi)
    #pragma unroll
    for (int ni = 0; ni < 4; ++ni)
      acc[mi][ni] = (f32x4){0.f, 0.f, 0.f, 0.f};

  for (int k0 = 0; k0 < K; k0 += 64) {
    #pragma unroll
    for (int i = 0; i < 4; ++i) {
      int slot = i * 256 + tid;
      int r = slot >> 3, cs = slot & 7;
      int c = cs ^ (r & 7);
      __builtin_amdgcn_global_load_lds(
          (const AS1 void*)(A + (size_t)(m0 + r) * K + k0 + c * 8),
          (AS3 void*)(a_sw + (i * 256 + w * 64) * 8), 16, 0, 0);
    }
    #pragma unroll
    for (int i = 0; i < 4; ++i) {
      int slot = i * 256 + tid;
      int r = slot >> 3, cs = slot & 7;
      int c = cs ^ (r & 7);
      __builtin_amdgcn_global_load_lds(
          (const AS1 void*)(Bt + (size_t)(n0 + r) * K + k0 + c * 8),
          (AS3 void*)(b_sw + (i * 256 + w * 64) * 8), 16, 0, 0);
    }
    __syncthreads();
    #pragma unroll
    for (int kk = 0; kk < 2; ++kk) {
      bf16x8v af[4], bv[4];
      #pragma unroll
      for (int mi = 0; mi < 4; ++mi) {
        int row = wr * 64 + mi * 16 + lm;
        af[mi] = *(const bf16x8v*)&a_sw[row * 64 + (((kk * 4 + lg) ^ (row & 7)) * 8)];
      }
      #pragma unroll
      for (int ni = 0; ni < 4; ++ni) {
        int row = wc * 64 + ni * 16 + lm;
        bv[ni] = *(const bf16x8v*)&b_sw[row * 64 + (((kk * 4 + lg) ^ (row & 7)) * 8)];
      }
      #pragma unroll
      for (int mi = 0; mi < 4; ++mi)
        #pragma unroll
        for (int ni = 0; ni < 4; ++ni)
          acc[mi][ni] = mfma16(af[mi], bv[ni], acc[mi][ni]);
    }
    __syncthreads();
  }
  #pragma unroll
  for (int mi = 0; mi < 4; ++mi) {
    #pragma unroll
    for (int ni = 0; ni < 4; ++ni) {
      int row = m0 + wr * 64 + mi * 16 + lg * 4;
      int col = n0 + wc * 64 + ni * 16 + lm;
      float bv_ = bias[col];
      #pragma unroll
      for (int j = 0; j < 4; ++j) {
        float o = acc[mi][ni][j] + bv_;
        if constexpr (RESMODE == 1)
          o += ((const float*)resv)[(size_t)(row + j) * N + col];
        if constexpr (RESMODE == 2)
          o += (float)((const bf16*)resv)[(size_t)(row + j) * N + col];
        if constexpr (GELU) {
          float z = 1.5957691216057308f * (o + 0.044715f * o * o * o);
          o = o / (1.0f + __expf(-z));
        }
        if constexpr (OUTF32)
          ((float*)outv)[(size_t)(row + j) * N + col] = o;
        else
          ((bf16*)outv)[(size_t)(row + j) * N + col] = (bf16)o;
      }
    }
  }
}

// ---------------- windowed attention (both branches) ------------------------
// qkv in attention-native layout [(b*3+m)*8+hh][tok][32]: Q/K fragments read
// contiguous 512B token-row runs; V staged coalesced into swizzled V^T.
__global__ __launch_bounds__(256) void k_attn(
    const bf16* __restrict__ qkv,
    const float* __restrict__ rpb1, const float* __restrict__ rpb2,
    bf16* __restrict__ aout) {
  __shared__ bf16 vt[128 * 72];   // V^T: [hh2*32+ch][token-swizzled(+pad)]
  __shared__ float rl[960];       // rpb: [h][dy][dx] stride 240/16/1

  int tid = threadIdx.x;
  int bx = blockIdx.x;
  int br = bx & 1, widx = (bx >> 1) & 63, b = bx >> 7;
  int wy = widx >> 3, wx = widx & 7;

  const float* rpb = br ? rpb2 : rpb1;
  #pragma unroll
  for (int t = tid; t < 960; t += 256) {
    int h0 = t / 240, r0 = t - h0 * 240, dy = r0 >> 4, dx = r0 & 15;
    rl[t] = (dx < 15) ? rpb[(dy * 15 + dx) * 4 + h0] : 0.f;
  }

  auto grow = [&](int tok) -> int {
    int y = wy * 8 + (tok >> 3), xc = wx * 8 + (tok & 7);
    if (br) { y = (y + 4) & 63; xc = (xc + 4) & 63; }
    return y * 64 + xc;                  // in-batch token index
  };

  // plane base for (m, head-in-branch hh2): ((b*3+m)*8 + br*4 + hh2) << 17
  auto plane = [&](int m, int hh2) -> size_t {
    return (size_t)((b * 3 + m) * 8 + br * 4 + hh2) << 17;
  };

  // stage V transposed: task = tok*16 + c; c = hh2*4 + ch8 (16 8ch-chunks)
  #pragma unroll
  for (int it = 0; it < 4; ++it) {
    int task = it * 256 + tid;
    int tok = task >> 4, c = task & 15;
    int hh2 = c >> 2, ch8 = c & 3;
    bf16x8v v = *(const bf16x8v*)&qkv[plane(2, hh2) + (grow(tok) << 5) + ch8 * 8];
    int tsw = tok ^ ((c & 7) << 3);      // bank-spread swizzle (involution)
    #pragma unroll
    for (int u = 0; u < 8; ++u) vt[(c * 8 + u) * 72 + tsw] = v[u];
  }

  int l = tid & 63, h = tid >> 6;
  int lm = l & 15, lg = l >> 4;

  // Q/K frags: token rows are 64B; 16 toks = 2 contiguous 512B runs
  bf16x8v kb[4], qa[4];
  size_t pq = plane(0, h), pk = plane(1, h);
  #pragma unroll
  for (int i = 0; i < 4; ++i) {
    int t = grow(i * 16 + lm);
    qa[i] = *(const bf16x8v*)&qkv[pq + (t << 5) + lg * 8];
    kb[i] = *(const bf16x8v*)&qkv[pk + (t << 5) + lg * 8];
  }
  __syncthreads();   // vt + rl ready

  // V B-frags for 16x16x16 PV (swizzled col, matching write involution)
  bf16x4v vb[2][4];
  #pragma unroll
  for (int ni = 0; ni < 2; ++ni)
    #pragma unroll
    for (int ki = 0; ki < 4; ++ki) {
      int row = h * 32 + ni * 16 + lm;
      int col = (ki * 16 + lg * 4) ^ (((row >> 3) & 7) << 3);
      vb[ni][ki] = *(const bf16x4v*)&vt[row * 72 + col];
    }

  bool need_mask = br && (wy == 7 || wx == 7);

  int ekA[16], idkA[16];
  #pragma unroll
  for (int ki = 0; ki < 4; ++ki)
    #pragma unroll
    for (int j = 0; j < 4; ++j) {
      int ik = ki * 16 + lg * 4 + j;
      ekA[ki * 4 + j] = ik + (ik >> 3) * 8;
      int yk = wy * 8 + (ik >> 3), xk = wx * 8 + (ik & 7);
      idkA[ki * 4 + j] = (yk < 56 ? 0 : (yk < 60 ? 1 : 2)) * 3
                       + (xk < 56 ? 0 : (xk < 60 ? 1 : 2));
    }

  #pragma unroll
  for (int qi = 0; qi < 4; ++qi) {
    f32x4 s[4];
    #pragma unroll
    for (int ki = 0; ki < 4; ++ki)
      s[ki] = mfma16(kb[ki], qa[qi], (f32x4){0.f,0.f,0.f,0.f});

    int iq = qi * 16 + lm;
    int eq = iq + (iq >> 3) * 8;
    int yq = wy * 8 + (iq >> 3), xq = wx * 8 + (iq & 7);
    int idq = (yq < 56 ? 0 : (yq < 60 ? 1 : 2)) * 3
            + (xq < 56 ? 0 : (xq < 60 ? 1 : 2));
    const float* fb = &rl[h * 240 + 119 + eq];

    #pragma unroll
    for (int ki = 0; ki < 4; ++ki)
      #pragma unroll
      for (int j = 0; j < 4; ++j) {
        float val = s[ki][j] * 0.17677669529663687f + fb[-ekA[ki * 4 + j]];
        if (need_mask && idq != idkA[ki * 4 + j]) val -= 100.0f;
        s[ki][j] = val;
      }

    float mx = s[0][0];
    #pragma unroll
    for (int ki = 0; ki < 4; ++ki)
      #pragma unroll
      for (int j = 0; j < 4; ++j) mx = fmaxf(mx, s[ki][j]);
    mx = fmaxf(mx, __shfl_xor(mx, 16));
    mx = fmaxf(mx, __shfl_xor(mx, 32));
    float sum = 0.f;
    #pragma unroll
    for (int ki = 0; ki < 4; ++ki)
      #pragma unroll
      for (int j = 0; j < 4; ++j) {
        float e = __expf(s[ki][j] - mx);
        s[ki][j] = e;
        sum += e;
      }
    sum += __shfl_xor(sum, 16);
    sum += __shfl_xor(sum, 32);
    float rs = 1.0f / sum;

    bf16x4v pa[4];
    #pragma unroll
    for (int ki = 0; ki < 4; ++ki)
      #pragma unroll
      for (int j = 0; j < 4; ++j)
        pa[ki][j] = (bf16)(s[ki][j] * rs);

    f32x4 o[2] = {(f32x4){0.f,0.f,0.f,0.f}, (f32x4){0.f,0.f,0.f,0.f}};
    #pragma unroll
    for (int ki = 0; ki < 4; ++ki) {
      o[0] = mfma16x16(pa[ki], vb[0][ki], o[0]);
      o[1] = mfma16x16(pa[ki], vb[1][ki], o[1]);
    }

    #pragma unroll
    for (int ni = 0; ni < 2; ++ni)
      #pragma unroll
      for (int j = 0; j < 4; ++j) {
        int tok = qi * 16 + lg * 4 + j;
        int col = br * 128 + h * 32 + ni * 16 + lm;
        aout[((size_t)b * 4096 + grow(tok)) * 256 + col] = (bf16)o[ni][j];
      }
  }
}

// ---------------- host ------------------------------------------------------
extern "C" void kernel_launch(void* const* d_in, const int* in_sizes, int n_in,
                              void* d_out, int out_size, void* d_ws, size_t ws_size,
                              hipStream_t stream) {
  (void)in_sizes; (void)n_in; (void)out_size; (void)ws_size;
  const float* x      = (const float*)d_in[0];
  const float* style  = (const float*)d_in[1];
  const float* w_qkv  = (const float*)d_in[2];
  const float* b_qkv  = (const float*)d_in[3];
  const float* w_proj = (const float*)d_in[4];
  const float* b_proj = (const float*)d_in[5];
  const float* w_ada1 = (const float*)d_in[6];
  const float* b_ada1 = (const float*)d_in[7];
  const float* w_ada2 = (const float*)d_in[8];
  const float* b_ada2 = (const float*)d_in[9];
  const float* rpb1   = (const float*)d_in[10];
  const float* rpb2   = (const float*)d_in[11];
  const float* w_fc1  = (const float*)d_in[12];
  const float* b_fc1  = (const float*)d_in[13];
  const float* w_fc2  = (const float*)d_in[14];
  const float* b_fc2  = (const float*)d_in[15];

  char* ws = (char*)d_ws;
  float* s1     = (float*)(ws + 0);
  float* s2     = (float*)(ws + 32768);
  float* scale1 = (float*)(ws + 65536);
  float* shift1 = (float*)(ws + 81920);
  float* scale2 = (float*)(ws + 98304);
  float* shift2 = (float*)(ws + 114688);
  bf16* wtqkv   = (bf16*)(ws + 131072);            // 768x256 bf16
  bf16* wtproj  = (bf16*)(ws + 524288);            // 256x256
  bf16* wtfc1   = (bf16*)(ws + 655360);            // 1024x256
  bf16* wtfc2   = (bf16*)(ws + 1179648);           // 256x1024
  float* psum   = (float*)(ws + 1703936);          // 16*16*256 f32
  float* psq    = (float*)(ws + 1966080);
  const size_t BIG = 2228224;
  bf16* xn   = (bf16*)(ws + BIG);                  // 65536x256 bf16 (33.5MB)
  bf16* qkv  = (bf16*)(ws + BIG + 33554432);       // 384 planes x 4096 x 32
  bf16* attn = (bf16*)(ws + BIG + 134217728);      // 65536x256 bf16 (33.5MB)
  bf16* x1   = (bf16*)(ws + BIG + 33554432);       // overlays qkv head
  bf16* xn2  = xn;                                 // reuses xn slot
  bf16* g    = (bf16*)(ws + BIG + 67108864);       // 32768x1024 chunk, qkv tail

  // weight transposes (f32 -> bf16)
  k_tr<<<dim3(24, 8),  256, 0, stream>>>(w_qkv,  wtqkv,  256, 768);
  k_tr<<<dim3(8, 8),   256, 0, stream>>>(w_proj, wtproj, 256, 256);
  k_tr<<<dim3(32, 8),  256, 0, stream>>>(w_fc1,  wtfc1,  256, 1024);
  k_tr<<<dim3(8, 32),  256, 0, stream>>>(w_fc2,  wtfc2,  1024, 256);

  // style projections, adain1 params, adain1 apply
  k_style<<<1024, 256, 0, stream>>>(style, w_ada1, b_ada1, w_ada2, b_ada2, s1, s2);
  k_stats_part<1><<<dim3(16, 16), 256, 0, stream>>>(x, psum, psq);
  k_stats_fin<<<16, 256, 0, stream>>>(psum, psq, s1, scale1, shift1);
  k_adain<1><<<8192, 256, 0, stream>>>(x, scale1, shift1, xn);

  // qkv = xn @ w_qkv + b_qkv  (attention-native output layout)
  k_gemm<0,0,2><<<1536, 512, 0, stream>>>(
      xn, wtqkv, b_qkv, nullptr, qkv, 768, 256, 6);

  // windowed attention (both branches)
  k_attn<<<2048, 256, 0, stream>>>(qkv, rpb1, rpb2, attn);

  // x1 = x + attn @ w_proj + b_proj   (128x128: 512 x 2 = 1024)
  k_gemm4<1,0,0><<<1024, 256, 0, stream>>>(
      attn, wtproj, b_proj, x, x1, 256, 256, 2);

  // adain2 params + apply
  k_stats_part<0><<<dim3(16, 16), 256, 0, stream>>>(x1, psum, psq);
  k_stats_fin<<<16, 256, 0, stream>>>(psum, psq, s2, scale2, shift2);
  k_adain<0><<<8192, 256, 0, stream>>>(x1, scale2, shift2, xn2);

  // MLP in 2 row-chunks of 32768 (g reuses dead qkv tail region)
  for (int ch = 0; ch < 2; ++ch) {
    size_t ro = (size_t)ch * 32768;
    // g = gelu(xn2 @ w_fc1 + b_fc1)   (256x128: 128 x 8 = 1024)
    k_gemm<0,1,0><<<1024, 512, 0, stream>>>(
        xn2 + ro * 256, wtfc1, b_fc1, nullptr, g, 1024, 256, 8);
    // out = x1 + g @ w_fc2 + b_fc2    (128x128: 256 x 2 = 512)
    k_gemm4<2,0,1><<<512, 256, 0, stream>>>(
        g, wtfc2, b_fc2, x1 + ro * 256,
        (float*)d_out + ro * 256, 256, 1024, 2);
  }
}